// Round 3
// baseline (216.970 us; speedup 1.0000x reference)
//
#include <hip/hip_runtime.h>
#include <math.h>

#define BB 8
#define CC 1024
#define HH 56
#define WW 56
#define NB 256
#define NCLS 30
#define BC (BB * CC)             // 8192 planes
#define PLANE (HH * WW)          // 3136
#define CELLS (HH * WW)          // 3136
#define NWORD (NB / 2)           // 128 packed u16-pairs per cell
#define SLICES 16
#define WSPLIT 2
#define WHALF (WW / WSPLIT)      // 28 columns per block
#define PL_PER_SLICE (BC / SLICES)                 // 512 planes
#define HTHREADS 256
#define VEC4_PER_BLOCK (PL_PER_SLICE * WHALF / 4)  // 3584 float4 loads/block
#define HIST_ITERS (VEC4_PER_BLOCK / HTHREADS)     // 14
#define LH_PITCH 129                               // +1 pad: bank=(wl+word)%32
#define LH_TOT (WHALF * LH_PITCH)                  // 3612 u32 (14.1 KB LDS)
#define FLUSH_N (NWORD * WHALF)                    // 3584 outputs per block

// ---------------------------------------------------------------------------
// Kernel 1: per-(h,w)-cell histograms, u16-packed in u32 words.
// Block = (whalf, h, slice). LDS hist lh[wl][129] (pad -> conflict-free both
// for random-bin atomics and linear flush reads). Depth-2 float4 prefetch
// keeps 2 global loads in flight across the LDS-atomic processing.
// Packing safety: per (cell,bin) count <= 512/slice, <= 8192 total < 65536.
// ps layout (non-atomic path): ps[word][slice][cell]  (cum2d reads contiguous)
// hp layout (atomic fallback):  hp[word][cell]
// ---------------------------------------------------------------------------
template <bool ATOMIC_FLUSH>
__global__ __launch_bounds__(HTHREADS) void hist_kernel(const float* __restrict__ x,
                                                        unsigned* __restrict__ dst) {
    __shared__ unsigned lh[LH_TOT];
    const int tid = threadIdx.x;
    const int bid = blockIdx.x;
    const int whalf = bid & (WSPLIT - 1);
    const int hs = bid / WSPLIT;  // slice*HH + h
    const int h = hs % HH;
    const int slice = hs / HH;

    for (int i = tid; i < LH_TOT; i += HTHREADS) lh[i] = 0u;
    __syncthreads();

    const float* __restrict__ xb =
        x + (size_t)(slice * PL_PER_SLICE) * PLANE + h * WW + whalf * WHALF;

    // j = it*256+tid in [0,3584): bcl = j/7 (plane in slice), wq = j%7 (float4)
    auto ldv = [&](int it) {
        const int j = it * HTHREADS + tid;
        const int bcl = j / 7;
        const int wq = j - bcl * 7;
        return *(const float4*)(xb + (size_t)bcl * PLANE + wq * 4);
    };
    auto wqof = [&](int it) {
        const int j = it * HTHREADS + tid;
        return j - (j / 7) * 7;
    };

    float4 b0 = ldv(0);
    float4 b1 = ldv(1);
#pragma unroll
    for (int it = 0; it < HIST_ITERS; ++it) {
        const float4 cur = b0;
        b0 = b1;
        if (it < HIST_ITERS - 2) b1 = ldv(it + 2);
        const int wl0 = wqof(it) * 4;
        const float vv[4] = {cur.x, cur.y, cur.z, cur.w};
#pragma unroll
        for (int e = 0; e < 4; ++e) {
            const float f = vv[e];
            if (f >= 0.f && f <= 1.f) {            // histc: out-of-range dropped
                int bin = (int)(f * 256.f);        // floor (f >= 0)
                if (bin > 255) bin = 255;          // v==1 -> last bin
                atomicAdd(&lh[(wl0 + e) * LH_PITCH + (bin >> 1)],
                          1u << ((bin & 1) << 4));
            }
        }
    }
    __syncthreads();

    // flush: i = word*WHALF + wl -> consecutive threads = consecutive wl
    for (int i = tid; i < FLUSH_N; i += HTHREADS) {
        const int word = i / WHALF;
        const int wl = i - word * WHALF;
        const unsigned v = lh[wl * LH_PITCH + word];
        const int cell = h * WW + whalf * WHALF + wl;
        if (ATOMIC_FLUSH) {
            if (v) atomicAdd(&dst[(size_t)word * CELLS + cell], v);
        } else {
            dst[((size_t)word * SLICES + slice) * CELLS + cell] = v;
        }
    }
}

// ---------------------------------------------------------------------------
// Kernel 2: fused slice-reduce + unpack + 2D inclusive prefix + store.
// One block per bin (256 blocks). Reads ps[word][slice][:] contiguous,
// unpacks its u16 lane, 2D-prefixes [56][56] in LDS, writes integ[h][w][bin].
// All integer-exact (u32).
// ---------------------------------------------------------------------------
template <int NSL>
__global__ __launch_bounds__(256) void cum2d_kernel(const unsigned* __restrict__ ps,
                                                    unsigned* __restrict__ integ) {
    __shared__ unsigned acc[CELLS];  // 12.5 KB
    const int bin = blockIdx.x;
    const int word = bin >> 1;
    const int sh = (bin & 1) << 4;
    const unsigned* __restrict__ base = ps + (size_t)word * NSL * CELLS;

    for (int c = threadIdx.x; c < CELLS; c += 256) {
        unsigned s = 0;
#pragma unroll
        for (int sl = 0; sl < NSL; ++sl) s += base[(size_t)sl * CELLS + c];
        acc[c] = (s >> sh) & 0xffffu;   // packed sum safe: each u16 lane <= 8192
    }
    __syncthreads();

    if (threadIdx.x < HH) {             // prefix over w (rows in parallel)
        unsigned run = 0;
        const int rb = threadIdx.x * WW;
        for (int w = 0; w < WW; ++w) { run += acc[rb + w]; acc[rb + w] = run; }
    }
    __syncthreads();
    if (threadIdx.x < WW) {             // prefix over h (cols in parallel)
        unsigned run = 0;
        for (int h = 0; h < HH; ++h) {
            run += acc[h * WW + threadIdx.x];
            acc[h * WW + threadIdx.x] = run;
        }
    }
    __syncthreads();

    for (int c = threadIdx.x; c < CELLS; c += 256)
        integ[(size_t)c * NB + bin] = acc[c];
}

// ---------------------------------------------------------------------------
// Kernel 3: EKLM decisions. 16 waves compute the 56 column entropies in
// parallel; wave 0 then does the argmax + greedy loop (wave-uniform).
// ---------------------------------------------------------------------------
__device__ __forceinline__ float wave_sum(float v) {
#pragma unroll
    for (int off = 32; off > 0; off >>= 1) v += __shfl_xor(v, off);
    return v;
}

__device__ __forceinline__ float ilook(const unsigned* __restrict__ integ,
                                       int a, int b, int bin) {
    return (a == 0 || b == 0)
               ? 0.f
               : (float)integ[((size_t)((a - 1) * WW + (b - 1))) * NB + bin];
}

__device__ float region_ent(const unsigned* __restrict__ integ, int lane,
                            int xd, int ys, int yd) {
    float hb[4];
    float hs = 0.f;
#pragma unroll
    for (int k = 0; k < 4; k++) {
        const int bin = lane + 64 * k;
        const float hv = ilook(integ, xd, yd, bin) - ilook(integ, xd, ys, bin);
        hb[k] = hv;
        hs += hv;
    }
    hs = wave_sum(hs);
    float e = 0.f;
#pragma unroll
    for (int k = 0; k < 4; k++) {
        const float p = hb[k] / hs;
        e += p * log2f(p + 1e-9f);
    }
    return -wave_sum(e);
}

__global__ __launch_bounds__(1024) void decide_kernel(const unsigned* __restrict__ integ,
                                                      int* __restrict__ region) {
    __shared__ float ent_s[WW];
    const int tid = threadIdx.x;
    const int lane = tid & 63;
    const int wv = tid >> 6;

    for (int w = wv; w < WW; w += 16) {
        float hb[4], hs = 0.f;
#pragma unroll
        for (int k = 0; k < 4; k++) {
            const int bin = lane + 64 * k;
            const float a = (float)integ[(size_t)w * NB + bin];
            const float b = w ? (float)integ[(size_t)(w - 1) * NB + bin] : 0.f;
            hb[k] = a - b;
            hs += hb[k];
        }
        hs = wave_sum(hs);
        float e = 0.f;
#pragma unroll
        for (int k = 0; k < 4; k++) {
            const float p = hb[k] / hs;
            e += p * log2f(p + 1e-9f);
        }
        e = -wave_sum(e);
        if (lane == 0) ent_s[w] = e;
    }
    __syncthreads();
    if (wv != 0) return;

    float best = -3.0e38f;
    int bestw = 0;
    for (int w = 0; w < WW; ++w) {
        const float e = ent_s[w];
        if (e > best) { best = e; bestw = w; }  // strict > keeps FIRST max
    }

    const float total_ent = region_ent(integ, lane, HH, 0, WW);

    int xd = 1, ys = bestw, yd = bestw + 1;
    float Ts = region_ent(integ, lane, xd, ys, yd) / total_ent;
    bool done = false;
    int iter = 0;
    while (Ts < 0.9f && !done && iter < 1000) {
        iter++;
        const float e_cur = region_ent(integ, lane, xd, ys, yd);
        const int ysm = (ys - 1 < 0) ? 0 : ys - 1;
        const int ydp = (yd + 1 > WW) ? WW : yd + 1;
        const bool c1 = (xd + 1 < HH) && (region_ent(integ, lane, xd + 1, ys, yd) > e_cur);
        const bool c2 = !c1 && (ys - 1 >= 0) && (region_ent(integ, lane, xd, ysm, yd) > e_cur);
        const bool c3 = !c1 && !c2 && (yd + 1 < WW) && (region_ent(integ, lane, xd, ys, ydp) > e_cur);
        if (c1) xd = xd + 1;
        else if (c2) ys = ys - 1;
        else if (c3) yd = yd + 1;
        done = !(c1 || c2 || c3);
        Ts = region_ent(integ, lane, xd, ys, yd) / total_ent;
    }

    if (lane == 0) {
        region[0] = xd;
        region[1] = ys;
        region[2] = yd;
    }
}

// ---------------------------------------------------------------------------
// Kernel 4: masked mean-pool — one wave per (b,c) plane, reads only region.
// ---------------------------------------------------------------------------
__global__ void pool_kernel(const float* __restrict__ x,
                            const int* __restrict__ region,
                            float* __restrict__ pooled) {
    const int bc = blockIdx.x;
    const int xd = region[0], ys = region[1], yd = region[2];
    const int Wd = yd - ys;
    const int n = xd * Wd;
    const float area = fmaxf((float)n, 1.f);
    const float* plane = x + (size_t)bc * PLANE;
    float s = 0.f;
    for (int j = threadIdx.x; j < n; j += 64) {
        const int r = j / Wd;
        const int cc = ys + (j - r * Wd);
        s += plane[r * WW + cc];
    }
#pragma unroll
    for (int off = 32; off > 0; off >>= 1) s += __shfl_xor(s, off);
    if (threadIdx.x == 0) pooled[bc] = s / area;
}

// ---------------------------------------------------------------------------
// Kernel 5: FC. Block = batch b; 8 c-chunks x 30 classes; LDS reduce.
// ---------------------------------------------------------------------------
__global__ __launch_bounds__(256) void fc_kernel(const float* __restrict__ pooled,
                                                 const float* __restrict__ wfc,
                                                 float* __restrict__ out) {
    __shared__ float red[240];
    const int b = blockIdx.x;
    const int t = threadIdx.x;
    if (t < 240) {
        const int chunk = t / NCLS;  // 0..7 -> c range [chunk*128, +128)
        const int n = t - chunk * NCLS;
        const float* pv = pooled + b * CC + chunk * 128;
        const float* wv = wfc + (size_t)(chunk * 128) * NCLS + n;
        float a0 = 0.f, a1 = 0.f, a2 = 0.f, a3 = 0.f;
        for (int c = 0; c < 128; c += 4) {
            a0 += pv[c + 0] * wv[(c + 0) * NCLS];
            a1 += pv[c + 1] * wv[(c + 1) * NCLS];
            a2 += pv[c + 2] * wv[(c + 2) * NCLS];
            a3 += pv[c + 3] * wv[(c + 3) * NCLS];
        }
        red[t] = (a0 + a1) + (a2 + a3);
    }
    __syncthreads();
    if (t < NCLS) {
        float s = 0.f;
#pragma unroll
        for (int ch = 0; ch < 8; ++ch) s += red[ch * NCLS + t];
        out[b * NCLS + t] = s;
    }
}

// ---------------------------------------------------------------------------
extern "C" void kernel_launch(void* const* d_in, const int* in_sizes, int n_in,
                              void* d_out, int out_size, void* d_ws, size_t ws_size,
                              hipStream_t stream) {
    const float* x = (const float*)d_in[0];    // [8,1024,56,56]
    const float* wfc = (const float*)d_in[1];  // [1024,30]
    float* out = (float*)d_out;                // [8,30]

    unsigned char* ws = (unsigned char*)d_ws;
    const size_t ps_bytes = (size_t)NWORD * SLICES * CELLS * 4;  // 25.7 MB
    const size_t integ_bytes = (size_t)CELLS * NB * 4;           // 3.2 MB
    const size_t needA = ps_bytes + integ_bytes + 4096 + (size_t)BC * 4;

    if (ws_size >= needA) {
        // Variant A: per-slice non-atomic flush + fused reduce/prefix
        unsigned* ps = (unsigned*)ws;
        unsigned* integ = (unsigned*)(ws + ps_bytes);
        int* region = (int*)(ws + ps_bytes + integ_bytes);
        float* pooled = (float*)(ws + ps_bytes + integ_bytes + 4096);

        hist_kernel<false><<<HH * WSPLIT * SLICES, HTHREADS, 0, stream>>>(x, ps);
        cum2d_kernel<SLICES><<<NB, 256, 0, stream>>>(ps, integ);
        decide_kernel<<<1, 1024, 0, stream>>>(integ, region);
        pool_kernel<<<BC, 64, 0, stream>>>(x, region, pooled);
        fc_kernel<<<BB, 256, 0, stream>>>(pooled, wfc, out);
    } else {
        // Variant B (small ws fallback): packed atomic flush into one hist
        unsigned* hp = (unsigned*)ws;  // [word][cell], 1.6 MB
        const size_t hp_bytes = (size_t)NWORD * CELLS * 4;
        unsigned* integ = (unsigned*)(ws + hp_bytes);
        int* region = (int*)(ws + hp_bytes + integ_bytes);
        float* pooled = (float*)(ws + hp_bytes + integ_bytes + 4096);

        hipMemsetAsync(hp, 0, hp_bytes, stream);
        hist_kernel<true><<<HH * WSPLIT * SLICES, HTHREADS, 0, stream>>>(x, hp);
        cum2d_kernel<1><<<NB, 256, 0, stream>>>(hp, integ);
        decide_kernel<<<1, 1024, 0, stream>>>(integ, region);
        pool_kernel<<<BC, 64, 0, stream>>>(x, region, pooled);
        fc_kernel<<<BB, 256, 0, stream>>>(pooled, wfc, out);
    }
}

// Round 4
// 193.538 us; speedup vs baseline: 1.1211x; 1.1211x over previous
//
#include <hip/hip_runtime.h>
#include <math.h>

#define BB 8
#define CC 1024
#define HH 56
#define WW 56
#define NB 256
#define NCLS 30
#define BC (BB * CC)             // 8192 planes
#define PLANE (HH * WW)          // 3136
#define CELLS (HH * WW)          // 3136
#define NWORD (NB / 2)           // 128 packed u16-pairs per cell
#define SLICES 8
#define WSPLIT 2
#define WHALF (WW / WSPLIT)      // 28 columns per block
#define PL_PER_SLICE (BC / SLICES)                 // 1024 planes
#define HTHREADS 256
#define VEC4_PER_BLOCK (PL_PER_SLICE * WHALF / 4)  // 7168 float4 loads/block
#define HIST_ITERS (VEC4_PER_BLOCK / HTHREADS)     // 28
#define LH_PITCH 129                               // +1 pad
#define LH_TOT (WHALF * LH_PITCH)                  // 3612 u32 (14.1 KB LDS)
#define FLUSH_N (NWORD * WHALF)                    // 3584 outputs per block

// ---------------------------------------------------------------------------
// Kernel 1: per-(h,w)-cell histograms, u16-packed in u32 words.
// Block = (whalf, h, slice); grid 896 = 3.5 blocks/CU, all co-resident.
// Round-2-style plain unrolled loop (compiler software-pipelines the 28
// independent float4 loads; manual prefetch regressed in round 3).
// Packing safety: per (cell,bin) count <= 1024/slice, sum <= 8192 < 65536.
// ps layout (non-atomic): ps[word][slice][cell]  -> cum2d reads contiguous.
// hp layout (atomic fallback): hp[word][cell].
// ---------------------------------------------------------------------------
template <bool ATOMIC_FLUSH>
__global__ __launch_bounds__(HTHREADS) void hist_kernel(const float* __restrict__ x,
                                                        unsigned* __restrict__ dst) {
    __shared__ unsigned lh[LH_TOT];
    const int tid = threadIdx.x;
    const int bid = blockIdx.x;
    const int whalf = bid & (WSPLIT - 1);
    const int hs = bid / WSPLIT;  // slice*HH + h
    const int h = hs % HH;
    const int slice = hs / HH;

    for (int i = tid; i < LH_TOT; i += HTHREADS) lh[i] = 0u;
    __syncthreads();

    const float* __restrict__ xb =
        x + (size_t)(slice * PL_PER_SLICE) * PLANE + h * WW + whalf * WHALF;

#pragma unroll
    for (int it = 0; it < HIST_ITERS; ++it) {      // 28 iters, compiler-pipelined
        const int j = it * HTHREADS + tid;         // [0, 7168)
        const int bcl = j / 7;                     // plane within slice
        const int wq = j - bcl * 7;                // float4 index in row-half
        const float4 v = *(const float4*)(xb + (size_t)bcl * PLANE + wq * 4);
        const float vv[4] = {v.x, v.y, v.z, v.w};
#pragma unroll
        for (int e = 0; e < 4; ++e) {
            const float f = vv[e];
            if (f >= 0.f && f <= 1.f) {            // histc: out-of-range dropped
                int bin = (int)(f * 256.f);        // floor (f >= 0)
                if (bin > 255) bin = 255;          // v==1 -> last bin
                atomicAdd(&lh[(wq * 4 + e) * LH_PITCH + (bin >> 1)],
                          1u << ((bin & 1) << 4));
            }
        }
    }
    __syncthreads();

    // flush: i = word*WHALF + wl -> consecutive threads = consecutive cells
    for (int i = tid; i < FLUSH_N; i += HTHREADS) {
        const int word = i / WHALF;
        const int wl = i - word * WHALF;
        const unsigned v = lh[wl * LH_PITCH + word];
        const int cell = h * WW + whalf * WHALF + wl;
        if (ATOMIC_FLUSH) {
            if (v) atomicAdd(&dst[(size_t)word * CELLS + cell], v);
        } else {
            dst[((size_t)word * SLICES + slice) * CELLS + cell] = v;
        }
    }
}

// ---------------------------------------------------------------------------
// Kernel 2: fused slice-reduce + unpack + 2D inclusive prefix.
// One block per bin. Reads ps[word][slice][:] contiguous (coalesced),
// 2D-prefixes [56][56] in LDS, stores integ[bin][cell] (coalesced — the
// round-3 [cell][bin] scatter was the regression). Integer-exact.
// ---------------------------------------------------------------------------
template <int NSL>
__global__ __launch_bounds__(256) void cum2d_kernel(const unsigned* __restrict__ ps,
                                                    unsigned* __restrict__ integ) {
    __shared__ unsigned acc[CELLS];  // 12.5 KB
    const int bin = blockIdx.x;
    const int word = bin >> 1;
    const int sh = (bin & 1) << 4;
    const unsigned* __restrict__ base = ps + (size_t)word * NSL * CELLS;

    for (int c = threadIdx.x; c < CELLS; c += 256) {
        unsigned s = 0;
#pragma unroll
        for (int sl = 0; sl < NSL; ++sl) s += base[(size_t)sl * CELLS + c];
        acc[c] = (s >> sh) & 0xffffu;  // packed sum safe: each lane <= 8192
    }
    __syncthreads();

    if (threadIdx.x < HH) {            // prefix over w (56 rows in parallel)
        unsigned run = 0;
        const int rb = threadIdx.x * WW;
        for (int w = 0; w < WW; ++w) { run += acc[rb + w]; acc[rb + w] = run; }
    }
    __syncthreads();
    if (threadIdx.x < WW) {            // prefix over h (56 cols in parallel)
        unsigned run = 0;
        for (int h = 0; h < HH; ++h) {
            run += acc[h * WW + threadIdx.x];
            acc[h * WW + threadIdx.x] = run;
        }
    }
    __syncthreads();

    unsigned* __restrict__ ob = integ + (size_t)bin * CELLS;
    for (int c = threadIdx.x; c < CELLS; c += 256) ob[c] = acc[c];
}

// ---------------------------------------------------------------------------
// Kernel 3: EKLM decisions on integ[bin][cell]. 16 waves for the 56 column
// entropies; wave 0 does argmax + greedy loop. Lane addresses are 12.5 KB
// strided (uncoalesced) — irrelevant, this kernel is latency-bound.
// ---------------------------------------------------------------------------
__device__ __forceinline__ float wave_sum(float v) {
#pragma unroll
    for (int off = 32; off > 0; off >>= 1) v += __shfl_xor(v, off);
    return v;
}

__device__ __forceinline__ float ilook(const unsigned* __restrict__ integ,
                                       int a, int b, int bin) {
    return (a == 0 || b == 0)
               ? 0.f
               : (float)integ[(size_t)bin * CELLS + (a - 1) * WW + (b - 1)];
}

__device__ float region_ent(const unsigned* __restrict__ integ, int lane,
                            int xd, int ys, int yd) {
    float hb[4];
    float hs = 0.f;
#pragma unroll
    for (int k = 0; k < 4; k++) {
        const int bin = lane + 64 * k;
        const float hv = ilook(integ, xd, yd, bin) - ilook(integ, xd, ys, bin);
        hb[k] = hv;
        hs += hv;
    }
    hs = wave_sum(hs);
    float e = 0.f;
#pragma unroll
    for (int k = 0; k < 4; k++) {
        const float p = hb[k] / hs;
        e += p * log2f(p + 1e-9f);
    }
    return -wave_sum(e);
}

__global__ __launch_bounds__(1024) void decide_kernel(const unsigned* __restrict__ integ,
                                                      int* __restrict__ region) {
    __shared__ float ent_s[WW];
    const int tid = threadIdx.x;
    const int lane = tid & 63;
    const int wv = tid >> 6;

    for (int w = wv; w < WW; w += 16) {
        float hb[4], hs = 0.f;
#pragma unroll
        for (int k = 0; k < 4; k++) {
            const int bin = lane + 64 * k;
            const float a = (float)integ[(size_t)bin * CELLS + w];
            const float b = w ? (float)integ[(size_t)bin * CELLS + w - 1] : 0.f;
            hb[k] = a - b;
            hs += hb[k];
        }
        hs = wave_sum(hs);
        float e = 0.f;
#pragma unroll
        for (int k = 0; k < 4; k++) {
            const float p = hb[k] / hs;
            e += p * log2f(p + 1e-9f);
        }
        e = -wave_sum(e);
        if (lane == 0) ent_s[w] = e;
    }
    __syncthreads();
    if (wv != 0) return;

    float best = -3.0e38f;
    int bestw = 0;
    for (int w = 0; w < WW; ++w) {
        const float e = ent_s[w];
        if (e > best) { best = e; bestw = w; }  // strict > keeps FIRST max
    }

    const float total_ent = region_ent(integ, lane, HH, 0, WW);

    int xd = 1, ys = bestw, yd = bestw + 1;
    float Ts = region_ent(integ, lane, xd, ys, yd) / total_ent;
    bool done = false;
    int iter = 0;
    while (Ts < 0.9f && !done && iter < 1000) {
        iter++;
        const float e_cur = region_ent(integ, lane, xd, ys, yd);
        const int ysm = (ys - 1 < 0) ? 0 : ys - 1;
        const int ydp = (yd + 1 > WW) ? WW : yd + 1;
        const bool c1 = (xd + 1 < HH) && (region_ent(integ, lane, xd + 1, ys, yd) > e_cur);
        const bool c2 = !c1 && (ys - 1 >= 0) && (region_ent(integ, lane, xd, ysm, yd) > e_cur);
        const bool c3 = !c1 && !c2 && (yd + 1 < WW) && (region_ent(integ, lane, xd, ys, ydp) > e_cur);
        if (c1) xd = xd + 1;
        else if (c2) ys = ys - 1;
        else if (c3) yd = yd + 1;
        done = !(c1 || c2 || c3);
        Ts = region_ent(integ, lane, xd, ys, yd) / total_ent;
    }

    if (lane == 0) {
        region[0] = xd;
        region[1] = ys;
        region[2] = yd;
    }
}

// ---------------------------------------------------------------------------
// Kernel 4: masked mean-pool — one wave per (b,c) plane, reads only region.
// ---------------------------------------------------------------------------
__global__ void pool_kernel(const float* __restrict__ x,
                            const int* __restrict__ region,
                            float* __restrict__ pooled) {
    const int bc = blockIdx.x;
    const int xd = region[0], ys = region[1], yd = region[2];
    const int Wd = yd - ys;
    const int n = xd * Wd;
    const float area = fmaxf((float)n, 1.f);
    const float* plane = x + (size_t)bc * PLANE;
    float s = 0.f;
    for (int j = threadIdx.x; j < n; j += 64) {
        const int r = j / Wd;
        const int cc = ys + (j - r * Wd);
        s += plane[r * WW + cc];
    }
#pragma unroll
    for (int off = 32; off > 0; off >>= 1) s += __shfl_xor(s, off);
    if (threadIdx.x == 0) pooled[bc] = s / area;
}

// ---------------------------------------------------------------------------
// Kernel 5: FC. Block = batch b; 8 c-chunks x 30 classes; LDS reduce.
// ---------------------------------------------------------------------------
__global__ __launch_bounds__(256) void fc_kernel(const float* __restrict__ pooled,
                                                 const float* __restrict__ wfc,
                                                 float* __restrict__ out) {
    __shared__ float red[240];
    const int b = blockIdx.x;
    const int t = threadIdx.x;
    if (t < 240) {
        const int chunk = t / NCLS;  // 0..7 -> c range [chunk*128, +128)
        const int n = t - chunk * NCLS;
        const float* pv = pooled + b * CC + chunk * 128;
        const float* wv = wfc + (size_t)(chunk * 128) * NCLS + n;
        float a0 = 0.f, a1 = 0.f, a2 = 0.f, a3 = 0.f;
        for (int c = 0; c < 128; c += 4) {
            a0 += pv[c + 0] * wv[(c + 0) * NCLS];
            a1 += pv[c + 1] * wv[(c + 1) * NCLS];
            a2 += pv[c + 2] * wv[(c + 2) * NCLS];
            a3 += pv[c + 3] * wv[(c + 3) * NCLS];
        }
        red[t] = (a0 + a1) + (a2 + a3);
    }
    __syncthreads();
    if (t < NCLS) {
        float s = 0.f;
#pragma unroll
        for (int ch = 0; ch < 8; ++ch) s += red[ch * NCLS + t];
        out[b * NCLS + t] = s;
    }
}

// ---------------------------------------------------------------------------
extern "C" void kernel_launch(void* const* d_in, const int* in_sizes, int n_in,
                              void* d_out, int out_size, void* d_ws, size_t ws_size,
                              hipStream_t stream) {
    const float* x = (const float*)d_in[0];    // [8,1024,56,56]
    const float* wfc = (const float*)d_in[1];  // [1024,30]
    float* out = (float*)d_out;                // [8,30]

    unsigned char* ws = (unsigned char*)d_ws;
    const size_t ps_bytes = (size_t)NWORD * SLICES * CELLS * 4;  // 12.9 MB
    const size_t integ_bytes = (size_t)NB * CELLS * 4;           // 3.2 MB
    const size_t needA = ps_bytes + integ_bytes + 4096 + (size_t)BC * 4;

    if (ws_size >= needA) {
        // Variant A: per-slice non-atomic flush + fused reduce/prefix
        unsigned* ps = (unsigned*)ws;
        unsigned* integ = (unsigned*)(ws + ps_bytes);
        int* region = (int*)(ws + ps_bytes + integ_bytes);
        float* pooled = (float*)(ws + ps_bytes + integ_bytes + 4096);

        hist_kernel<false><<<HH * WSPLIT * SLICES, HTHREADS, 0, stream>>>(x, ps);
        cum2d_kernel<SLICES><<<NB, 256, 0, stream>>>(ps, integ);
        decide_kernel<<<1, 1024, 0, stream>>>(integ, region);
        pool_kernel<<<BC, 64, 0, stream>>>(x, region, pooled);
        fc_kernel<<<BB, 256, 0, stream>>>(pooled, wfc, out);
    } else {
        // Variant B (small ws fallback): packed atomic flush into one hist
        unsigned* hp = (unsigned*)ws;  // [word][cell], 1.6 MB
        const size_t hp_bytes = (size_t)NWORD * CELLS * 4;
        unsigned* integ = (unsigned*)(ws + hp_bytes);
        int* region = (int*)(ws + hp_bytes + integ_bytes);
        float* pooled = (float*)(ws + hp_bytes + integ_bytes + 4096);

        hipMemsetAsync(hp, 0, hp_bytes, stream);
        hist_kernel<true><<<HH * WSPLIT * SLICES, HTHREADS, 0, stream>>>(x, hp);
        cum2d_kernel<1><<<NB, 256, 0, stream>>>(hp, integ);
        decide_kernel<<<1, 1024, 0, stream>>>(integ, region);
        pool_kernel<<<BC, 64, 0, stream>>>(x, region, pooled);
        fc_kernel<<<BB, 256, 0, stream>>>(pooled, wfc, out);
    }
}